// Round 1
// baseline (94.084 us; speedup 1.0000x reference)
//
#include <hip/hip_runtime.h>

#define GRIDC 32

__global__ void cd_zero_ws(double* ws) {
    if (threadIdx.x == 0 && blockIdx.x == 0) ws[0] = 0.0;
}

__global__ __launch_bounds__(256) void cd_main(
    const float* __restrict__ point, const float* __restrict__ CP,
    const float* __restrict__ tsdfOut, const float* __restrict__ tsdfGT,
    const int* __restrict__ inUse, double* __restrict__ ws)
{
    // B=128, NP=32, NS=2048 -> N = 65536 points per batch, total 8388608
    const long long total = 8388608LL;
    const long long nGroups = total >> 2; // groups of 4 points

    float lsum = 0.0f;
    const long long stride = (long long)gridDim.x * blockDim.x;
    for (long long g = (long long)blockIdx.x * blockDim.x + threadIdx.x; g < nGroups; g += stride) {
        const long long i0 = g << 2; // first point index of this group (mult of 4)
        // 4 points = 12 contiguous floats = 3 aligned float4 loads
        const float4* pbase = (const float4*)(point + i0 * 3);
        const float4 pA = pbase[0], pB = pbase[1], pC = pbase[2];
        const float px[4] = {pA.x, pA.w, pB.z, pC.y};
        const float py[4] = {pA.y, pB.x, pB.w, pC.z};
        const float pz[4] = {pA.z, pB.y, pC.x, pC.w};
        const float4 to4 = *(const float4*)(tsdfOut + i0);
        const float4 tg4 = *(const float4*)(tsdfGT + i0);

        const int b = (int)(i0 >> 16);            // / 65536
        const int n = (int)(i0 & 65535);
        // NS=2048 is a multiple of 4 -> same primitive for all 4 points
        const int use = inUse[(b << 5) + (n >> 11)];

        if (use == 1) {
            const float* cpb = CP + (long long)b * (GRIDC * GRIDC * GRIDC * 3);
            #pragma unroll
            for (int k = 0; k < 4; ++k) {
                const float x = px[k], y = py[k], z = pz[k];
                // (p + 0.5) * 32, truncate toward zero (matches .astype(int32)), clamp [0,31]
                int ix = (int)((x + 0.5f) * 32.0f);
                int iy = (int)((y + 0.5f) * 32.0f);
                int iz = (int)((z + 0.5f) * 32.0f);
                ix = min(max(ix, 0), 31);
                iy = min(max(iy, 0), 31);
                iz = min(max(iz, 0), 31);
                const float* c = cpb + ((ix * GRIDC + iy) * GRIDC + iz) * 3;
                const float dx = x - c[0];
                const float dy = y - c[1];
                const float dz = z - c[2];
                lsum += sqrtf(dx * dx + dy * dy + dz * dz);
            }
        }
        // tsdf term (always counted)
        lsum += fabsf(sqrtf(to4.x) - tg4.x);
        lsum += fabsf(sqrtf(to4.y) - tg4.y);
        lsum += fabsf(sqrtf(to4.z) - tg4.z);
        lsum += fabsf(sqrtf(to4.w) - tg4.w);
    }

    // wave64 butterfly-free down-shuffle reduce
    #pragma unroll
    for (int off = 32; off > 0; off >>= 1)
        lsum += __shfl_down(lsum, off, 64);

    __shared__ float wsum[4];
    const int lane = threadIdx.x & 63;
    const int wid  = threadIdx.x >> 6;
    if (lane == 0) wsum[wid] = lsum;
    __syncthreads();
    if (threadIdx.x == 0) {
        const float bsum = wsum[0] + wsum[1] + wsum[2] + wsum[3];
        atomicAdd(ws, (double)bsum);
    }
}

__global__ void cd_finalize(const double* __restrict__ ws, float* __restrict__ out) {
    if (threadIdx.x == 0 && blockIdx.x == 0)
        out[0] = (float)(ws[0] / 8388608.0);
}

extern "C" void kernel_launch(void* const* d_in, const int* in_sizes, int n_in,
                              void* d_out, int out_size, void* d_ws, size_t ws_size,
                              hipStream_t stream) {
    const float* point   = (const float*)d_in[0];
    const float* CP      = (const float*)d_in[1];
    const float* tsdfOut = (const float*)d_in[2];
    const float* tsdfGT  = (const float*)d_in[3];
    const int*   inUse   = (const int*)d_in[4];
    double* ws  = (double*)d_ws;
    float*  out = (float*)d_out;

    hipLaunchKernelGGL(cd_zero_ws, dim3(1), dim3(64), 0, stream, ws);
    hipLaunchKernelGGL(cd_main, dim3(2048), dim3(256), 0, stream,
                       point, CP, tsdfOut, tsdfGT, inUse, ws);
    hipLaunchKernelGGL(cd_finalize, dim3(1), dim3(64), 0, stream, ws, out);
}